// Round 4
// baseline (28.524 us; speedup 1.0000x reference)
//
#include <hip/hip_runtime.h>

// SNN autoencoder collapses to: m_e = x @ enc_w ; m_d = m_e @ dec_w
// (spike state is exactly {0,1}, so 0.9*s - 0.9*(s>0.9) == 0 every step;
//  membranes are recomputed from the constant input current each step).
// Output: d_out = [m_d (2048x1024) | m_e (2048x256)], fp32.
//
// 3 dispatches:
//   prep_t : enc->bf16 transposed [N][K], dec->bf16 transposed [N][K] (512 blocks)
//   gemm1  : m_e = x @ enc_w — A staged as f32 straight from x (inline bf16 cvt),
//            3-buffer counted-vmcnt pipeline (never drains vmcnt to 0 in loop)
//   gemm2  : m_d = m_e @ dec_w (K=256 LDS-resident, 1 barrier, 1024 blocks)

typedef __attribute__((ext_vector_type(8))) short bf16x8;
typedef __attribute__((ext_vector_type(4))) float f32x4;
typedef __attribute__((ext_vector_type(8))) unsigned short ushort8;

__device__ __forceinline__ unsigned short f2bf(float f) {
    unsigned u = __builtin_bit_cast(unsigned, f);
    unsigned r = u + 0x7FFFu + ((u >> 16) & 1u);   // RNE
    return (unsigned short)(r >> 16);
}

// ---- stage ROWS x 64 bf16 tile (8 chunks/row, XOR-swizzled source, rule #21) ----
template <int ROWS>
__device__ __forceinline__ void stage_tile(const unsigned short* __restrict__ g,
                                           int ld, unsigned short* lds, int t) {
    #pragma unroll
    for (int c = 0; c < ROWS / 32; ++c) {
        const int idx = c * 256 + t;          // 16B-chunk index in tile
        const int row = idx >> 3;
        const int chunk = (idx & 7) ^ (row & 7);
        const unsigned short* src = g + (size_t)row * ld + chunk * 8;
        unsigned short* dst = lds + (size_t)(idx & ~63) * 8;  // wave-uniform base
        __builtin_amdgcn_global_load_lds(
            (const __attribute__((address_space(1))) void*)src,
            (__attribute__((address_space(3))) void*)dst, 16, 0, 0);
    }
}

// ---- stage ROWS x 64 f32 tile (16 chunks/row, XOR-swizzled source) ----
template <int ROWS>
__device__ __forceinline__ void stage_tile_f32(const float* __restrict__ g,
                                               int ld, float* lds, int t) {
    #pragma unroll
    for (int c = 0; c < ROWS / 16; ++c) {
        const int idx = c * 256 + t;          // 16B-chunk index in tile
        const int row = idx >> 4;             // 16 chunks per row
        const int chunk = (idx & 15) ^ (row & 15);
        const float* src = g + (size_t)row * ld + chunk * 4;
        float* dst = lds + (size_t)(idx & ~63) * 4;           // wave-uniform base
        __builtin_amdgcn_global_load_lds(
            (const __attribute__((address_space(1))) void*)src,
            (__attribute__((address_space(3))) void*)dst, 16, 0, 0);
    }
}

// ---------------- GEMM1: 32x32 tiles, 3-buffer counted-vmcnt pipeline ----------
// A = x [2048][1024] f32 (cvt inline), B = encT [256][1024] bf16.
// Per wave per tile: 2 A-loads + 1 B-load = 3 vmem instrs -> steady wait vmcnt(3).
__global__ __launch_bounds__(256) void gemm1_pipe(
    const float* __restrict__ x,            // [2048][1024] f32
    const unsigned short* __restrict__ Bt,  // [256][1024] bf16 (encT)
    float* __restrict__ C,                  // [2048][256] f32 (m_e)
    unsigned short* __restrict__ Cbf)       // [2048][256] bf16
{
    constexpr int N = 256, K = 1024, BK = 64, NT = K / BK;
    __shared__ __align__(16) float          As[3][32 * 64];  // 8 KB each
    __shared__ __align__(16) unsigned short Bs[3][32 * 64];  // 4 KB each

    const int t = threadIdx.x;
    const int lane = t & 63;
    const int l15 = lane & 15, l4 = lane >> 4;
    const int wid = t >> 6;
    const int wr = wid >> 1, wc = wid & 1;          // 2x2 waves, WM=WN=16
    const int brow = blockIdx.y * 32, bcol = blockIdx.x * 32;

    const float* Ab = x + (size_t)brow * K;
    const unsigned short* Bb = Bt + (size_t)bcol * K;

    f32x4 acc = {0.f, 0.f, 0.f, 0.f};

    // prologue: stage tiles 0 and 1
    stage_tile_f32<32>(Ab, K, As[0], t);
    stage_tile<32>(Bb, K, Bs[0], t);
    stage_tile_f32<32>(Ab + BK, K, As[1], t);
    stage_tile<32>(Bb + BK, K, Bs[1], t);

    for (int kt = 0; kt < NT; ++kt) {
        // tile kt's 3 loads complete; tile kt+1's 3 stay in flight (T4)
        if (kt + 1 < NT) { asm volatile("s_waitcnt vmcnt(3)" ::: "memory"); }
        else             { asm volatile("s_waitcnt vmcnt(0)" ::: "memory"); }
        __builtin_amdgcn_s_barrier();
        __builtin_amdgcn_sched_barrier(0);

        if (kt + 2 < NT) {   // prefetch tile kt+2 into buf[(kt+2)%3] (= buf[(kt-1)%3])
            const int nb = (kt + 2) % 3;
            stage_tile_f32<32>(Ab + (kt + 2) * BK, K, As[nb], t);
            stage_tile<32>(Bb + (kt + 2) * BK, K, Bs[nb], t);
        }

        const int cur = kt % 3;
        const int ra = wr * 16 + l15;          // A row (r & 15 == l15)
        const int rb = wc * 16 + l15;          // B row
        #pragma unroll
        for (int s = 0; s < 2; ++s) {
            // A: 8 consecutive f32 = chunks (s*8+l4*2)^l15, +1^l15
            const int c0 = (s * 8 + l4 * 2) ^ l15;
            const int c1 = (s * 8 + l4 * 2 + 1) ^ l15;
            const f32x4 a0 = *(const f32x4*)&As[cur][ra * 64 + c0 * 4];
            const f32x4 a1 = *(const f32x4*)&As[cur][ra * 64 + c1 * 4];
            bf16x8 aF;
            aF[0] = (short)f2bf(a0[0]); aF[1] = (short)f2bf(a0[1]);
            aF[2] = (short)f2bf(a0[2]); aF[3] = (short)f2bf(a0[3]);
            aF[4] = (short)f2bf(a1[0]); aF[5] = (short)f2bf(a1[1]);
            aF[6] = (short)f2bf(a1[2]); aF[7] = (short)f2bf(a1[3]);
            const int cb = (s * 4 + l4) ^ (rb & 7);
            const bf16x8 bF = *(const bf16x8*)&Bs[cur][rb * 64 + cb * 8];
            acc = __builtin_amdgcn_mfma_f32_16x16x32_bf16(aF, bF, acc, 0, 0, 0);
        }
    }

    #pragma unroll
    for (int reg = 0; reg < 4; ++reg) {
        const int row = brow + wr * 16 + l4 * 4 + reg;
        const int col = bcol + wc * 16 + l15;
        const float v = acc[reg];
        C[(size_t)row * N + col] = v;
        Cbf[(size_t)row * N + col] = f2bf(v);
    }
}

// ---------------- GEMM2: K=256 LDS-resident, single barrier ----------------
__global__ __launch_bounds__(256) void gemm2_kres(
    const unsigned short* __restrict__ A,   // [2048][256] bf16 (m_e)
    const unsigned short* __restrict__ B,   // [1024][256] bf16 (decT)
    float* __restrict__ C)                  // [2048][1024] f32 (m_d)
{
    constexpr int K = 256, N = 1024;
    __shared__ __align__(16) unsigned short As[4][32 * 64];  // 16 KB
    __shared__ __align__(16) unsigned short Bs[4][64 * 64];  // 32 KB

    const int t = threadIdx.x;
    const int lane = t & 63;
    const int l15 = lane & 15, l4 = lane >> 4;
    const int wid = t >> 6;
    const int wr = wid >> 1, wc = wid & 1;
    const int brow = blockIdx.y * 32, bcol = blockIdx.x * 64;

    #pragma unroll
    for (int kt = 0; kt < 4; ++kt) {
        stage_tile<32>(A + (size_t)brow * K + kt * 64, K, As[kt], t);
        stage_tile<64>(B + (size_t)bcol * K + kt * 64, K, Bs[kt], t);
    }
    __syncthreads();

    f32x4 acc[2] = {{0.f, 0.f, 0.f, 0.f}, {0.f, 0.f, 0.f, 0.f}};
    #pragma unroll
    for (int kt = 0; kt < 4; ++kt)
        #pragma unroll
        for (int s = 0; s < 2; ++s) {
            const int ra = wr * 16 + l15;
            const int cha = (s * 4 + l4) ^ (ra & 7);
            bf16x8 aF = *(const bf16x8*)&As[kt][ra * 64 + cha * 8];
            #pragma unroll
            for (int j = 0; j < 2; ++j) {
                const int rb = wc * 32 + j * 16 + l15;
                const int chb = (s * 4 + l4) ^ (rb & 7);
                bf16x8 bF = *(const bf16x8*)&Bs[kt][rb * 64 + chb * 8];
                acc[j] = __builtin_amdgcn_mfma_f32_16x16x32_bf16(aF, bF, acc[j], 0, 0, 0);
            }
        }

    #pragma unroll
    for (int j = 0; j < 2; ++j)
        #pragma unroll
        for (int reg = 0; reg < 4; ++reg) {
            const int row = brow + wr * 16 + l4 * 4 + reg;
            const int col = bcol + wc * 32 + j * 16 + l15;
            C[(size_t)row * N + col] = acc[j][reg];
        }
}

// ---------------- prep: enc transpose | dec transpose (512 blocks) ----------
__global__ __launch_bounds__(256) void prep_t(
    const float* __restrict__ enc, const float* __restrict__ dec,
    unsigned short* __restrict__ encT, unsigned short* __restrict__ decT)
{
    __shared__ unsigned short tile[32][33];
    const int bid = blockIdx.x;
    const int t = threadIdx.x;

    const float* in; unsigned short* out; int R, C, bx, by;
    if (bid < 256) {                // enc [1024][256] -> encT [256][1024]
        in = enc; out = encT; R = 1024; C = 256; bx = bid % 8; by = bid / 8;
    } else {                        // dec [256][1024] -> decT [1024][256]
        const int bb = bid - 256;
        in = dec; out = decT; R = 256; C = 1024; bx = bb % 32; by = bb / 32;
    }
    const int r0 = by * 32, c0 = bx * 32;
    const int tx = t % 32, ty = t / 32;       // 32 x 8
    #pragma unroll
    for (int k = 0; k < 4; ++k) {
        const int lr = ty + k * 8;
        tile[lr][tx] = f2bf(in[(size_t)(r0 + lr) * C + c0 + tx]);
    }
    __syncthreads();
    #pragma unroll
    for (int k = 0; k < 4; ++k) {
        const int lc = ty + k * 8;
        out[(size_t)(c0 + lc) * R + r0 + tx] = tile[tx][lc];
    }
}

// ---------------- fp32 fallback ----------------
#define BKF 32
#define PADF 4
template <int BM, int BN, int TM, int TN>
__global__ __launch_bounds__(256) void gemm_f32(
    const float* __restrict__ A, const float* __restrict__ B,
    float* __restrict__ C, int M, int N, int K)
{
    __shared__ float As[BKF][BM + PADF];
    __shared__ float Bs[BKF][BN + PADF];
    const int t = threadIdx.x;
    const int brow = blockIdx.y * BM, bcol = blockIdx.x * BN;
    constexpr int NTX = BN / TN;
    const int tx = t % NTX, ty = t / NTX;
    float acc[TM][TN];
    #pragma unroll
    for (int i = 0; i < TM; ++i)
        #pragma unroll
        for (int j = 0; j < TN; ++j) acc[i][j] = 0.f;
    for (int k0 = 0; k0 < K; k0 += BKF) {
        #pragma unroll
        for (int v = t; v < BM * BKF / 4; v += 256) {
            const int row = v / (BKF / 4), kv = v % (BKF / 4);
            const float4 val = *(const float4*)&A[(size_t)(brow + row) * K + k0 + kv * 4];
            As[kv * 4 + 0][row] = val.x; As[kv * 4 + 1][row] = val.y;
            As[kv * 4 + 2][row] = val.z; As[kv * 4 + 3][row] = val.w;
        }
        #pragma unroll
        for (int v = t; v < BKF * BN / 4; v += 256) {
            const int kk = v / (BN / 4), cv = v % (BN / 4);
            *(float4*)&Bs[kk][cv * 4] = *(const float4*)&B[(size_t)(k0 + kk) * N + bcol + cv * 4];
        }
        __syncthreads();
        #pragma unroll
        for (int k = 0; k < BKF; ++k) {
            float a[TM], b[TN];
            #pragma unroll
            for (int i = 0; i < TM; ++i) a[i] = As[k][ty * TM + i];
            #pragma unroll
            for (int j = 0; j < TN; ++j) b[j] = Bs[k][tx * TN + j];
            #pragma unroll
            for (int i = 0; i < TM; ++i)
                #pragma unroll
                for (int j = 0; j < TN; ++j) acc[i][j] = fmaf(a[i], b[j], acc[i][j]);
        }
        __syncthreads();
    }
    #pragma unroll
    for (int i = 0; i < TM; ++i)
        #pragma unroll
        for (int j = 0; j < TN; ++j)
            C[(size_t)(brow + ty * TM + i) * N + bcol + tx * TN + j] = acc[i][j];
}

extern "C" void kernel_launch(void* const* d_in, const int* in_sizes, int n_in,
                              void* d_out, int out_size, void* d_ws, size_t ws_size,
                              hipStream_t stream) {
    const float* x     = (const float*)d_in[0];  // [2048, 1024]
    const float* enc_w = (const float*)d_in[1];  // [1024, 256]
    const float* dec_w = (const float*)d_in[2];  // [256, 1024]

    const int B = 2048, D = 1024, H = 256;
    float* m_d = (float*)d_out;
    float* m_e = (float*)d_out + (size_t)B * D;

    const size_t need = (size_t)D * H * 2 * 2 + (size_t)B * H * 2;
    if (ws_size >= need) {
        unsigned short* encT  = (unsigned short*)d_ws;            // [256][1024]
        unsigned short* decT  = encT + (size_t)H * D;             // [1024][256]
        unsigned short* me_bf = decT + (size_t)D * H;             // [2048][256]

        prep_t<<<dim3(512), dim3(256), 0, stream>>>(enc_w, dec_w, encT, decT);

        // m_e = x @ enc_w : M=2048 N=256 K=1024, 32x32 tiles -> 512 blocks
        gemm1_pipe<<<dim3(H / 32, B / 32), dim3(256), 0, stream>>>(x, encT, m_e, me_bf);
        // m_d = m_e @ dec_w : K-resident, 32x64 tiles -> 1024 blocks
        gemm2_kres<<<dim3(D / 64, B / 32), dim3(256), 0, stream>>>(me_bf, decT, m_d);
    } else {
        gemm_f32<64, 32, 4, 2><<<dim3(H / 32, B / 64), dim3(256), 0, stream>>>(x, enc_w, m_e, B, H, D);
        gemm_f32<64, 64, 4, 4><<<dim3(D / 64, B / 64), dim3(256), 0, stream>>>(m_e, dec_w, m_d, B, D, H);
    }
}